// Round 3
// baseline (191.792 us; speedup 1.0000x reference)
//
#include <hip/hip_runtime.h>
#include <hip/hip_bf16.h>

// Sizes (fixed): B=128, M=1024, D_Z=1024, D_PHI=512, H1=512, H2=512
// ws: hzb f32[128*512] @0 (256KB) | hpb bf16[1024*512] @256K (1MB) |
//     W2T bf16[512*512] @1.25M (512KB) | hz_part f32[2][128*512] @1.75M (512KB)

typedef __bf16 bf16x8 __attribute__((ext_vector_type(8)));
typedef float  f32x4  __attribute__((ext_vector_type(4)));

// tanh-form GELU (max dev from exact erf ~5e-4)
__device__ __forceinline__ float gelu_f(float x) {
    float t = x * x;
    float inner = __builtin_fmaf(0.044715f * t, x, x);
    float e = __builtin_amdgcn_exp2f(2.3022082f * inner);
    float r = __builtin_amdgcn_rcpf(e + 1.0f);
    return __builtin_fmaf(-x, r, x);
}

__device__ __forceinline__ unsigned int pack_bf16x2(float a, float b) {
    __hip_bfloat162 h = __float22bfloat162_rn(make_float2(a, b));
    return *reinterpret_cast<unsigned int*>(&h);
}
__device__ __forceinline__ float bf_lo(unsigned int u) {
    return __builtin_bit_cast(float, u << 16);
}
__device__ __forceinline__ float bf_hi(unsigned int u) {
    return __builtin_bit_cast(float, u & 0xffff0000u);
}

// ---------------- prep: hz partials / hpb(bf16) / W2T ----------------
// grid 384 x 256:
//   [0,64):    W2T 64x64 transpose-cast tiles
//   [64,320):  hpb tiles 32r x 64c, K=512        (256 blocks)
//   [320,384): hz  tiles 32r x 64c, K-split 2x512 (64 blocks) -> hz_part
__global__ __launch_bounds__(256) void prep_kernel(
    const float* __restrict__ g_q, const float* __restrict__ Phi,
    const float* __restrict__ W1, const float* __restrict__ W2,
    unsigned short* __restrict__ hpb, unsigned short* __restrict__ W2T,
    float* __restrict__ hz_part)
{
    __shared__ float smem[4608];   // 18 KB (w2t needs 64*68=4352, gemm 32*128=4096)
    const int t = threadIdx.x;
    const int id = blockIdx.x;

    if (id < 64) {
        // ----- W2T[n][k] = bf16(W2[k][n]) via 64x64 tile, pad 68 -----
        const int kt = id >> 3, nt = id & 7;
        const int k0 = kt * 64, n0 = nt * 64;
        {
            int r = t >> 2, c16 = (t & 3) * 16;
            #pragma unroll
            for (int q = 0; q < 4; ++q)
                *(float4*)&smem[r * 68 + c16 + q * 4] =
                    *(const float4*)&W2[(k0 + r) * 512 + n0 + c16 + q * 4];
        }
        __syncthreads();
        int nl = t >> 2, kc = (t & 3) * 16;
        unsigned int pk[8];
        #pragma unroll
        for (int i = 0; i < 8; ++i) {
            float f0 = smem[(kc + 2 * i    ) * 68 + nl];
            float f1 = smem[(kc + 2 * i + 1) * 68 + nl];
            pk[i] = pack_bf16x2(f0, f1);
        }
        unsigned int idx = (unsigned int)(n0 + nl) * 512u + (unsigned int)(k0 + kc);
        *(uint4*)&W2T[idx]     = make_uint4(pk[0], pk[1], pk[2], pk[3]);
        *(uint4*)&W2T[idx + 8] = make_uint4(pk[4], pk[5], pk[6], pk[7]);
    } else if (id < 320) {
        // ----- hpb = bf16(Phi @ W1[1024:]) : tile 32r x 64c -----
        const int id2 = id - 64;
        const int rt = id2 >> 3, ct = id2 & 7;
        const int r0 = rt * 32, c0 = ct * 64;
        const int c  = c0 + (t & 63);
        const int rg = t >> 6;                  // 0..3, wave-uniform
        float acc8[8];
        #pragma unroll
        for (int rr = 0; rr < 8; ++rr) acc8[rr] = 0.f;

        for (int kc = 0; kc < 512; kc += 128) {
            __syncthreads();
            #pragma unroll
            for (int q = 0; q < 4; ++q) {        // stage Phi[32][128]
                int i = (q * 256 + t) * 4;
                int r = i >> 7, j = i & 127;
                *(float4*)&smem[i] = *(const float4*)&Phi[(r0 + r) * 512 + kc + j];
            }
            __syncthreads();
            #pragma unroll 4
            for (int j4 = 0; j4 < 128; j4 += 4) {
                float w0 = W1[(1024 + kc + j4 + 0) * 512 + c];
                float w1 = W1[(1024 + kc + j4 + 1) * 512 + c];
                float w2 = W1[(1024 + kc + j4 + 2) * 512 + c];
                float w3 = W1[(1024 + kc + j4 + 3) * 512 + c];
                #pragma unroll
                for (int rr = 0; rr < 8; ++rr) {
                    float4 p = *(const float4*)&smem[(rg * 8 + rr) * 128 + j4];
                    float s = acc8[rr];
                    s = __builtin_fmaf(p.x, w0, s);
                    s = __builtin_fmaf(p.y, w1, s);
                    s = __builtin_fmaf(p.z, w2, s);
                    s = __builtin_fmaf(p.w, w3, s);
                    acc8[rr] = s;
                }
            }
        }
        #pragma unroll
        for (int rr = 0; rr < 8; ++rr) {
            __hip_bfloat16 v = __float2bfloat16(acc8[rr]);
            hpb[(r0 + rg * 8 + rr) * 512 + c] = *reinterpret_cast<unsigned short*>(&v);
        }
    } else {
        // ----- hz_part[ks] = g_q @ W1[ks*512 : +512] : tile 32r x 64c -----
        const int id3 = id - 320;
        const int ks = id3 >> 5;                // 0..1
        const int rt = (id3 >> 3) & 3, ct = id3 & 7;
        const int r0 = rt * 32, c0 = ct * 64;
        const int kb = ks * 512;
        const int c  = c0 + (t & 63);
        const int rg = t >> 6;
        float acc8[8];
        #pragma unroll
        for (int rr = 0; rr < 8; ++rr) acc8[rr] = 0.f;

        for (int kc = 0; kc < 512; kc += 128) {
            __syncthreads();
            #pragma unroll
            for (int q = 0; q < 4; ++q) {        // stage g_q[32][128]
                int i = (q * 256 + t) * 4;
                int r = i >> 7, j = i & 127;
                *(float4*)&smem[i] = *(const float4*)&g_q[(r0 + r) * 1024 + kb + kc + j];
            }
            __syncthreads();
            #pragma unroll 4
            for (int j4 = 0; j4 < 128; j4 += 4) {
                float w0 = W1[(kb + kc + j4 + 0) * 512 + c];
                float w1 = W1[(kb + kc + j4 + 1) * 512 + c];
                float w2 = W1[(kb + kc + j4 + 2) * 512 + c];
                float w3 = W1[(kb + kc + j4 + 3) * 512 + c];
                #pragma unroll
                for (int rr = 0; rr < 8; ++rr) {
                    float4 p = *(const float4*)&smem[(rg * 8 + rr) * 128 + j4];
                    float s = acc8[rr];
                    s = __builtin_fmaf(p.x, w0, s);
                    s = __builtin_fmaf(p.y, w1, s);
                    s = __builtin_fmaf(p.z, w2, s);
                    s = __builtin_fmaf(p.w, w3, s);
                    acc8[rr] = s;
                }
            }
        }
        float* part = hz_part + ks * 65536;
        #pragma unroll
        for (int rr = 0; rr < 8; ++rr)
            part[(r0 + rg * 8 + rr) * 512 + c] = acc8[rr];
    }
}

// ---------------- combine: hzb = hz_part[0] + hz_part[1] + b1 ----------------
__global__ __launch_bounds__(256) void combine_kernel(
    const float* __restrict__ hz_part, const float* __restrict__ b1,
    float* __restrict__ hzb)
{
    int i = (blockIdx.x * 256 + threadIdx.x) * 4;   // 64 blocks -> 65536 elems
    float4 a = *(const float4*)&hz_part[i];
    float4 b = *(const float4*)&hz_part[65536 + i];
    float4 bb = *(const float4*)&b1[i & 511];
    float4 o;
    o.x = a.x + b.x + bb.x;
    o.y = a.y + b.y + bb.y;
    o.z = a.z + b.z + bb.z;
    o.w = a.w + b.w + bb.w;
    *(float4*)&hzb[i] = o;
}

// ---------------- fused: gelu1 -> bf16 GEMM (x W2) -> gelu2 -> dot W3 ----------------
// Block: 128 rows x 512 cols, 512 thr (8 waves), wave tile 128x64 (acc 8x4 f32x4).
// A (gelu1 out) in LDS, double-buffered 2x16KB, XOR-swizzled. B (W2T) loaded
// global->registers per kt (L2-resident, no LDS, no vmcnt-drain coupling).
// ONE barrier per kt: body = { B(kt) reg loads | AGEN(kt+1) | MFMA(kt) } barrier.
__global__ __launch_bounds__(512, 2) void fused_kernel(
    const float* __restrict__ hzb, const unsigned short* __restrict__ hpb,
    const unsigned short* __restrict__ W2T,
    const float* __restrict__ b2, const float* __restrict__ W3,
    const float* __restrict__ b3, float* __restrict__ out)
{
    __shared__ __align__(16) unsigned short lA[2 * 128 * 64]; // 32 KB
    __shared__ __align__(16) float lhz[512];
    __shared__ float lred[8][128];

    const int t = threadIdx.x;
    const int w = t >> 6;           // wave 0..7 = col group (64 cols each)
    const int l = t & 63;
    const int r0 = blockIdx.x * 128;
    const int b  = r0 >> 10;
    const int m0 = r0 & 1023;

    lhz[t] = hzb[b * 512 + t];

    f32x4 acc[8][4];
    #pragma unroll
    for (int a = 0; a < 8; ++a)
        #pragma unroll
        for (int bf = 0; bf < 4; ++bf)
            acc[a][bf] = f32x4{0.f, 0.f, 0.f, 0.f};

    // AGEN mapping: wave halves cover rows, chunk = (w&3) and (w&3)+4
    const int arow = ((w >> 2) << 6) + l;       // 0..127
    const int acb  = w & 3;
    const unsigned short* hprow = hpb + (unsigned)(m0 + arow) * 512;
    const float4* lhz4 = (const float4*)lhz;

    auto AGEN = [&](int kt, int buf) {
        const int k0 = kt * 64;
        #pragma unroll
        for (int h = 0; h < 2; ++h) {
            int c  = acb + 4 * h;
            int kb = k0 + c * 8;
            uint4 hv = *(const uint4*)&hprow[kb];
            float4 z0 = lhz4[kb >> 2];
            float4 z1 = lhz4[(kb >> 2) + 1];
            float g0 = gelu_f(bf_lo(hv.x) + z0.x);
            float g1 = gelu_f(bf_hi(hv.x) + z0.y);
            float g2 = gelu_f(bf_lo(hv.y) + z0.z);
            float g3 = gelu_f(bf_hi(hv.y) + z0.w);
            float g4 = gelu_f(bf_lo(hv.z) + z1.x);
            float g5 = gelu_f(bf_hi(hv.z) + z1.y);
            float g6 = gelu_f(bf_lo(hv.w) + z1.z);
            float g7 = gelu_f(bf_hi(hv.w) + z1.w);
            uint4 pk;
            pk.x = pack_bf16x2(g0, g1);
            pk.y = pack_bf16x2(g2, g3);
            pk.z = pack_bf16x2(g4, g5);
            pk.w = pack_bf16x2(g6, g7);
            *(uint4*)((char*)lA + (unsigned)(buf * 16384 + arow * 128 +
                                             ((c ^ (arow & 7)) << 4))) = pk;
        }
    };

    __syncthreads();          // lhz visible
    AGEN(0, 0);
    __syncthreads();          // lA[0] ready

    #pragma unroll 1
    for (int kt = 0; kt < 8; ++kt) {
        const int k0 = kt * 64;

        // --- B(kt): 8 x global_load_dwordx4 into regs (issue early) ---
        uint4 breg[2][4];
        #pragma unroll
        for (int kk = 0; kk < 2; ++kk)
            #pragma unroll
            for (int bf = 0; bf < 4; ++bf) {
                int n = w * 64 + 16 * bf + (l & 15);
                breg[kk][bf] = *(const uint4*)
                    &W2T[(unsigned)(n * 512 + k0 + kk * 32 + ((l >> 4) << 3))];
            }

        // --- AGEN(kt+1) hides B latency + overlaps MFMA pipe ---
        if (kt < 7) AGEN(kt + 1, (kt + 1) & 1);

        // --- MFMA(kt): A from LDS, B from regs ---
        const char* abase = (const char*)lA + (kt & 1) * 16384;
        #pragma unroll
        for (int kk = 0; kk < 2; ++kk) {
            const int cch = kk * 4 + (l >> 4);
            bf16x8 af[8];
            #pragma unroll
            for (int a = 0; a < 8; ++a) {
                int row = 16 * a + (l & 15);
                unsigned off = (unsigned)(row * 128 + ((cch ^ (row & 7)) << 4));
                af[a] = __builtin_bit_cast(bf16x8, *(const uint4*)(abase + off));
            }
            #pragma unroll
            for (int bf = 0; bf < 4; ++bf) {
                bf16x8 bfr = __builtin_bit_cast(bf16x8, breg[kk][bf]);
                #pragma unroll
                for (int a = 0; a < 8; ++a)
                    acc[a][bf] = __builtin_amdgcn_mfma_f32_16x16x32_bf16(
                        af[a], bfr, acc[a][bf], 0, 0, 0);
            }
        }

        __syncthreads();      // lA[(kt+1)&1] ready / lA[kt&1] free
    }

    // ---- epilogue: +b2, gelu2, dot W3, reduce ----
    float b2v[4], w3v[4];
    #pragma unroll
    for (int bf = 0; bf < 4; ++bf) {
        int n = w * 64 + 16 * bf + (l & 15);
        b2v[bf] = b2[n];
        w3v[bf] = W3[n];
    }
    float psum[8][4];
    #pragma unroll
    for (int a = 0; a < 8; ++a)
        #pragma unroll
        for (int r = 0; r < 4; ++r) psum[a][r] = 0.f;

    #pragma unroll
    for (int bf = 0; bf < 4; ++bf)
        #pragma unroll
        for (int a = 0; a < 8; ++a)
            #pragma unroll
            for (int r = 0; r < 4; ++r) {
                float x = acc[a][bf][r] + b2v[bf];
                float h = gelu_f(x);
                psum[a][r] = __builtin_fmaf(h, w3v[bf], psum[a][r]);
            }

    #pragma unroll
    for (int a = 0; a < 8; ++a)
        #pragma unroll
        for (int r = 0; r < 4; ++r) {
            float v = psum[a][r];
            v += __shfl_xor(v, 1);
            v += __shfl_xor(v, 2);
            v += __shfl_xor(v, 4);
            v += __shfl_xor(v, 8);
            psum[a][r] = v;
        }

    if ((l & 15) == 0) {
        int gb = (l >> 4) * 4;
        #pragma unroll
        for (int a = 0; a < 8; ++a)
            #pragma unroll
            for (int r = 0; r < 4; ++r)
                lred[w][16 * a + gb + r] = psum[a][r];
    }
    __syncthreads();
    if (t < 128) {
        float s = b3[0];
        #pragma unroll
        for (int ww = 0; ww < 8; ++ww) s += lred[ww][t];
        out[r0 + t] = s;
    }
}

extern "C" void kernel_launch(void* const* d_in, const int* in_sizes, int n_in,
                              void* d_out, int out_size, void* d_ws, size_t ws_size,
                              hipStream_t stream) {
    (void)in_sizes; (void)n_in; (void)out_size; (void)ws_size;
    const float* g_q = (const float*)d_in[0];
    const float* Phi = (const float*)d_in[1];
    const float* W1  = (const float*)d_in[2];
    const float* b1  = (const float*)d_in[3];
    const float* W2  = (const float*)d_in[4];
    const float* b2  = (const float*)d_in[5];
    const float* W3  = (const float*)d_in[6];
    const float* b3  = (const float*)d_in[7];
    float* out = (float*)d_out;

    char* ws = (char*)d_ws;
    float*          hzb     = (float*)ws;                        // 256 KB
    unsigned short* hpb     = (unsigned short*)(ws + (256 << 10));          // 1 MB
    unsigned short* W2T     = (unsigned short*)(ws + (256 << 10) + (1 << 20)); // 512 KB
    float*          hz_part = (float*)(ws + (256 << 10) + (1 << 20) + (512 << 10)); // 512 KB

    hipLaunchKernelGGL(prep_kernel, dim3(384), dim3(256), 0, stream,
                       g_q, Phi, W1, W2, hpb, W2T, hz_part);
    hipLaunchKernelGGL(combine_kernel, dim3(64), dim3(256), 0, stream,
                       hz_part, b1, hzb);
    hipLaunchKernelGGL(fused_kernel, dim3(1024), dim3(512), 0, stream,
                       hzb, hpb, W2T, b2, W3, b3, out);
}

// Round 4
// 169.389 us; speedup vs baseline: 1.1323x; 1.1323x over previous
//
#include <hip/hip_runtime.h>
#include <hip/hip_bf16.h>

// Sizes (fixed): B=128, M=1024, D_Z=1024, D_PHI=512, H1=512, H2=512
// ws: hzb f32[128*512] @0 (256KB) | hpb bf16[1024*512] @256K (1MB) |
//     W2F bf16[512*512] @1.25M (512KB, MFMA-frag-contiguous layout)
//
// W2F layout: B-fragment for (kc = k>>5, nf = n>>4) is 1024B contiguous:
//   addr_ushort = (kc*32 + nf)*512 + lane*8,  lane = (n&15) + 16*((k>>3)&3)
//   lane holds W2[k..k+7][n] (i.e. W2T[n][k..+8]) -> exact 16x16x32 B-frag.

typedef __bf16 bf16x8 __attribute__((ext_vector_type(8)));
typedef float  f32x4  __attribute__((ext_vector_type(4)));

// tanh-form GELU (max dev from exact erf ~5e-4)
__device__ __forceinline__ float gelu_f(float x) {
    float t = x * x;
    float inner = __builtin_fmaf(0.044715f * t, x, x);
    float e = __builtin_amdgcn_exp2f(2.3022082f * inner);
    float r = __builtin_amdgcn_rcpf(e + 1.0f);
    return __builtin_fmaf(-x, r, x);
}

__device__ __forceinline__ unsigned int pack_bf16x2(float a, float b) {
    __hip_bfloat162 h = __float22bfloat162_rn(make_float2(a, b));
    return *reinterpret_cast<unsigned int*>(&h);
}
__device__ __forceinline__ float bf_lo(unsigned int u) {
    return __builtin_bit_cast(float, u << 16);
}
__device__ __forceinline__ float bf_hi(unsigned int u) {
    return __builtin_bit_cast(float, u & 0xffff0000u);
}

// ---------------- prep: W2F frags / hpb(bf16) / hzb(f32,+b1) ----------------
// grid 640 x 256:
//   [0,64):    W2F 64x64 transpose-cast -> frag layout
//   [64,576):  hpb tiles 16r x 64c, K=512   (512 blocks)
//   [576,640): hzb tiles 16r x 64c, K=1024  (64 blocks), += b1
__global__ __launch_bounds__(256) void prep_kernel(
    const float* __restrict__ g_q, const float* __restrict__ Phi,
    const float* __restrict__ W1, const float* __restrict__ b1,
    const float* __restrict__ W2,
    unsigned short* __restrict__ hpb, unsigned short* __restrict__ W2F,
    float* __restrict__ hzb)
{
    __shared__ float smem[4352];   // 17 KB (W2F branch: 64*68; GEMM: 16*128)
    const int t = threadIdx.x;
    const int id = blockIdx.x;

    if (id < 64) {
        // ----- W2F: read W2 64x64 tile, emit frag-contiguous bf16 -----
        const int kt = id >> 3, nt = id & 7;
        const int k0 = kt * 64, n0 = nt * 64;
        {
            int r = t >> 2, c16 = (t & 3) * 16;
            #pragma unroll
            for (int q = 0; q < 4; ++q)
                *(float4*)&smem[r * 68 + c16 + q * 4] =
                    *(const float4*)&W2[(k0 + r) * 512 + n0 + c16 + q * 4];
        }
        __syncthreads();
        const int nl = t >> 2, kc16 = (t & 3) * 16;
        unsigned int pk[8];
        #pragma unroll
        for (int i = 0; i < 8; ++i) {
            float f0 = smem[(kc16 + 2 * i    ) * 68 + nl];
            float f1 = smem[(kc16 + 2 * i + 1) * 68 + nl];
            pk[i] = pack_bf16x2(f0, f1);
        }
        const int n  = n0 + nl;
        const int nf = n >> 4;
        #pragma unroll
        for (int h = 0; h < 2; ++h) {
            int kbase = k0 + kc16 + h * 8;
            int kc = kbase >> 5;
            int k8 = (kbase >> 3) & 3;
            int lane = (n & 15) + 16 * k8;
            uint4 v = h ? make_uint4(pk[4], pk[5], pk[6], pk[7])
                        : make_uint4(pk[0], pk[1], pk[2], pk[3]);
            *(uint4*)&W2F[(unsigned)((kc * 32 + nf) * 512 + lane * 8)] = v;
        }
    } else if (id < 576) {
        // ----- hpb = bf16(Phi @ W1[1024:]) : tile 16r x 64c -----
        const int id2 = id - 64;
        const int rt = id2 >> 3, ct = id2 & 7;
        const int r0 = rt * 16, c0 = ct * 64;
        const int c  = c0 + (t & 63);
        const int rg = t >> 6;                  // 4 groups x 4 rows
        float acc4[4] = {0.f, 0.f, 0.f, 0.f};

        for (int kc = 0; kc < 512; kc += 128) {
            __syncthreads();
            {
                int i = t * 8;
                int r = i >> 7, j = i & 127;
                *(float4*)&smem[i]     = *(const float4*)&Phi[(r0 + r) * 512 + kc + j];
                *(float4*)&smem[i + 4] = *(const float4*)&Phi[(r0 + r) * 512 + kc + j + 4];
            }
            __syncthreads();
            #pragma unroll 4
            for (int j4 = 0; j4 < 128; j4 += 4) {
                float w0 = W1[(1024 + kc + j4 + 0) * 512 + c];
                float w1 = W1[(1024 + kc + j4 + 1) * 512 + c];
                float w2 = W1[(1024 + kc + j4 + 2) * 512 + c];
                float w3 = W1[(1024 + kc + j4 + 3) * 512 + c];
                #pragma unroll
                for (int rr = 0; rr < 4; ++rr) {
                    float4 p = *(const float4*)&smem[(rg * 4 + rr) * 128 + j4];
                    float s = acc4[rr];
                    s = __builtin_fmaf(p.x, w0, s);
                    s = __builtin_fmaf(p.y, w1, s);
                    s = __builtin_fmaf(p.z, w2, s);
                    s = __builtin_fmaf(p.w, w3, s);
                    acc4[rr] = s;
                }
            }
        }
        #pragma unroll
        for (int rr = 0; rr < 4; ++rr) {
            __hip_bfloat16 v = __float2bfloat16(acc4[rr]);
            hpb[(r0 + rg * 4 + rr) * 512 + c] = *reinterpret_cast<unsigned short*>(&v);
        }
    } else {
        // ----- hzb = g_q @ W1[:1024] + b1 : tile 16r x 64c -----
        const int id3 = id - 576;
        const int rt = id3 >> 3, ct = id3 & 7;
        const int r0 = rt * 16, c0 = ct * 64;
        const int c  = c0 + (t & 63);
        const int rg = t >> 6;
        float acc4[4] = {0.f, 0.f, 0.f, 0.f};

        for (int kc = 0; kc < 1024; kc += 128) {
            __syncthreads();
            {
                int i = t * 8;
                int r = i >> 7, j = i & 127;
                *(float4*)&smem[i]     = *(const float4*)&g_q[(r0 + r) * 1024 + kc + j];
                *(float4*)&smem[i + 4] = *(const float4*)&g_q[(r0 + r) * 1024 + kc + j + 4];
            }
            __syncthreads();
            #pragma unroll 4
            for (int j4 = 0; j4 < 128; j4 += 4) {
                float w0 = W1[(kc + j4 + 0) * 512 + c];
                float w1 = W1[(kc + j4 + 1) * 512 + c];
                float w2 = W1[(kc + j4 + 2) * 512 + c];
                float w3 = W1[(kc + j4 + 3) * 512 + c];
                #pragma unroll
                for (int rr = 0; rr < 4; ++rr) {
                    float4 p = *(const float4*)&smem[(rg * 4 + rr) * 128 + j4];
                    float s = acc4[rr];
                    s = __builtin_fmaf(p.x, w0, s);
                    s = __builtin_fmaf(p.y, w1, s);
                    s = __builtin_fmaf(p.z, w2, s);
                    s = __builtin_fmaf(p.w, w3, s);
                    acc4[rr] = s;
                }
            }
        }
        float bb = b1[c];
        #pragma unroll
        for (int rr = 0; rr < 4; ++rr)
            hzb[(r0 + rg * 4 + rr) * 512 + c] = acc4[rr] + bb;
    }
}

// ---------------- fused: gelu1 -> bf16 GEMM (x W2) -> gelu2 -> dot W3 ----------------
// Block: 64 rows x 512 cols, 512 thr (8 waves), wave tile 64x64 (acc 4x4).
// A (gelu1) in LDS double-buffered 2x8KB XOR-swizzled; B frags loaded
// global->reg from W2F (coalesced 1KB/frag, L2-resident). ONE barrier per kt.
__global__ __launch_bounds__(512, 2) void fused_kernel(
    const float* __restrict__ hzb, const unsigned short* __restrict__ hpb,
    const unsigned short* __restrict__ W2F,
    const float* __restrict__ b2, const float* __restrict__ W3,
    const float* __restrict__ b3, float* __restrict__ out)
{
    __shared__ __align__(16) unsigned short lA[2 * 64 * 64]; // 16 KB
    __shared__ __align__(16) float lhz[512];
    __shared__ float lred[8][64];

    const int t = threadIdx.x;
    const int w = t >> 6;            // wave = col group (64 cols)
    const int l = t & 63;
    const int r0 = blockIdx.x * 64;
    const int b  = r0 >> 10;
    const int m0 = r0 & 1023;

    lhz[t] = hzb[b * 512 + t];

    f32x4 acc[4][4];
    #pragma unroll
    for (int a = 0; a < 4; ++a)
        #pragma unroll
        for (int bf = 0; bf < 4; ++bf)
            acc[a][bf] = f32x4{0.f, 0.f, 0.f, 0.f};

    // AGEN mapping: thread -> (row = t>>3, chunk = t&7); 1 uint4 of hpb per kt
    const int arow = t >> 3;
    const int ac   = t & 7;
    const unsigned short* hprow = hpb + (unsigned)(m0 + arow) * 512;
    const float4* lhz4 = (const float4*)lhz;
    const unsigned int awoff = (unsigned)(arow * 128 + ((ac ^ (arow & 7)) << 4));

    auto AGEN = [&](uint4 hv, int kt, int buf) {
        const int kb = kt * 64 + ac * 8;
        float4 z0 = lhz4[kb >> 2];
        float4 z1 = lhz4[(kb >> 2) + 1];
        float g0 = gelu_f(bf_lo(hv.x) + z0.x);
        float g1 = gelu_f(bf_hi(hv.x) + z0.y);
        float g2 = gelu_f(bf_lo(hv.y) + z0.z);
        float g3 = gelu_f(bf_hi(hv.y) + z0.w);
        float g4 = gelu_f(bf_lo(hv.z) + z1.x);
        float g5 = gelu_f(bf_hi(hv.z) + z1.y);
        float g6 = gelu_f(bf_lo(hv.w) + z1.z);
        float g7 = gelu_f(bf_hi(hv.w) + z1.w);
        uint4 pk;
        pk.x = pack_bf16x2(g0, g1);
        pk.y = pack_bf16x2(g2, g3);
        pk.z = pack_bf16x2(g4, g5);
        pk.w = pack_bf16x2(g6, g7);
        *(uint4*)((char*)lA + (unsigned)(buf * 8192) + awoff) = pk;
    };

    // ---- prologue ----
    uint4 hv0 = *(const uint4*)&hprow[ac * 8];          // kt=0 slice
    __syncthreads();            // lhz visible
    AGEN(hv0, 0, 0);
    __syncthreads();            // lA[0] ready

    // ---- main loop: one barrier per kt ----
    #pragma unroll 2
    for (int kt = 0; kt < 8; ++kt) {
        // B(kt) frags: 8 coalesced dwordx4 from W2F (consumed by MFMA below)
        uint4 breg[2][4];
        #pragma unroll
        for (int kk = 0; kk < 2; ++kk)
            #pragma unroll
            for (int bf = 0; bf < 4; ++bf)
                breg[kk][bf] = *(const uint4*)
                    &W2F[(unsigned)(((kt * 2 + kk) * 32 + w * 4 + bf) * 512 + l * 8)];

        // AGEN(kt+1) into the other buffer (hides B latency, feeds next kt)
        if (kt < 7) {
            uint4 hvn = *(const uint4*)&hprow[(kt + 1) * 64 + ac * 8];
            AGEN(hvn, kt + 1, (kt + 1) & 1);
        }

        // MFMA(kt): A from lA[kt&1], B from regs
        const char* abase = (const char*)lA + (kt & 1) * 8192;
        #pragma unroll
        for (int kk = 0; kk < 2; ++kk) {
            const int cch = kk * 4 + (l >> 4);
            bf16x8 af[4];
            #pragma unroll
            for (int a = 0; a < 4; ++a) {
                int row = 16 * a + (l & 15);
                unsigned off = (unsigned)(row * 128 + ((cch ^ (row & 7)) << 4));
                af[a] = __builtin_bit_cast(bf16x8, *(const uint4*)(abase + off));
            }
            #pragma unroll
            for (int bf = 0; bf < 4; ++bf) {
                bf16x8 bfr = __builtin_bit_cast(bf16x8, breg[kk][bf]);
                #pragma unroll
                for (int a = 0; a < 4; ++a)
                    acc[a][bf] = __builtin_amdgcn_mfma_f32_16x16x32_bf16(
                        af[a], bfr, acc[a][bf], 0, 0, 0);
            }
        }

        __syncthreads();        // lA[(kt+1)&1] ready; lA[kt&1] free for AGEN(kt+2)
    }

    // ---- epilogue: +b2, gelu2, dot W3, reduce ----
    float b2v[4], w3v[4];
    #pragma unroll
    for (int bf = 0; bf < 4; ++bf) {
        int n = w * 64 + 16 * bf + (l & 15);
        b2v[bf] = b2[n];
        w3v[bf] = W3[n];
    }
    float psum[4][4];
    #pragma unroll
    for (int a = 0; a < 4; ++a)
        #pragma unroll
        for (int r = 0; r < 4; ++r) psum[a][r] = 0.f;

    #pragma unroll
    for (int bf = 0; bf < 4; ++bf)
        #pragma unroll
        for (int a = 0; a < 4; ++a)
            #pragma unroll
            for (int r = 0; r < 4; ++r) {
                float x = acc[a][bf][r] + b2v[bf];
                float h = gelu_f(x);
                psum[a][r] = __builtin_fmaf(h, w3v[bf], psum[a][r]);
            }

    #pragma unroll
    for (int a = 0; a < 4; ++a)
        #pragma unroll
        for (int r = 0; r < 4; ++r) {
            float v = psum[a][r];
            v += __shfl_xor(v, 1);
            v += __shfl_xor(v, 2);
            v += __shfl_xor(v, 4);
            v += __shfl_xor(v, 8);
            psum[a][r] = v;
        }

    if ((l & 15) == 0) {
        int gb = (l >> 4) * 4;
        #pragma unroll
        for (int a = 0; a < 4; ++a)
            #pragma unroll
            for (int r = 0; r < 4; ++r)
                lred[w][16 * a + gb + r] = psum[a][r];
    }
    __syncthreads();
    if (t < 64) {
        float s = b3[0];
        #pragma unroll
        for (int ww = 0; ww < 8; ++ww) s += lred[ww][t];
        out[r0 + t] = s;
    }
}

extern "C" void kernel_launch(void* const* d_in, const int* in_sizes, int n_in,
                              void* d_out, int out_size, void* d_ws, size_t ws_size,
                              hipStream_t stream) {
    (void)in_sizes; (void)n_in; (void)out_size; (void)ws_size;
    const float* g_q = (const float*)d_in[0];
    const float* Phi = (const float*)d_in[1];
    const float* W1  = (const float*)d_in[2];
    const float* b1  = (const float*)d_in[3];
    const float* W2  = (const float*)d_in[4];
    const float* b2  = (const float*)d_in[5];
    const float* W3  = (const float*)d_in[6];
    const float* b3  = (const float*)d_in[7];
    float* out = (float*)d_out;

    char* ws = (char*)d_ws;
    float*          hzb = (float*)ws;                                   // 256 KB
    unsigned short* hpb = (unsigned short*)(ws + (256 << 10));          // 1 MB
    unsigned short* W2F = (unsigned short*)(ws + (256 << 10) + (1 << 20)); // 512 KB

    hipLaunchKernelGGL(prep_kernel, dim3(640), dim3(256), 0, stream,
                       g_q, Phi, W1, b1, W2, hpb, W2F, hzb);
    hipLaunchKernelGGL(fused_kernel, dim3(2048), dim3(512), 0, stream,
                       hzb, hpb, W2F, b2, W3, b3, out);
}

// Round 5
// 136.980 us; speedup vs baseline: 1.4001x; 1.2366x over previous
//
#include <hip/hip_runtime.h>
#include <hip/hip_bf16.h>

// Sizes (fixed): B=128, M=1024, D_Z=1024, D_PHI=512, H1=512, H2=512
// ws: hzb f32[128*512] @0 (256KB) | hpb bf16[1024*512] @256K (1MB) |
//     W2F bf16[512*512] @1.25M (512KB) | W1F bf16[1536*512] @1.75M (1.5MB)
//
// Frag layout (both W1F and W2F): B-fragment for (kc = k>>5, nf = n>>4) is
// 1024B contiguous: addr_ushort = (kc*NF + nf)*512 + lane*8,
//   lane = (n&15) + 16*((k>>3)&3), holds W[k..k+7][n]  (exact 16x16x32 B-frag).
// W2F: NF=32, kc 0..15.  W1F: NF=32, kc 0..47 (K=1536).

typedef __bf16 bf16x8 __attribute__((ext_vector_type(8)));
typedef float  f32x4  __attribute__((ext_vector_type(4)));

// tanh-form GELU (max dev from exact erf ~5e-4)
__device__ __forceinline__ float gelu_f(float x) {
    float t = x * x;
    float inner = __builtin_fmaf(0.044715f * t, x, x);
    float e = __builtin_amdgcn_exp2f(2.3022082f * inner);
    float r = __builtin_amdgcn_rcpf(e + 1.0f);
    return __builtin_fmaf(-x, r, x);
}

__device__ __forceinline__ unsigned int pack_bf16x2(float a, float b) {
    __hip_bfloat162 h = __float22bfloat162_rn(make_float2(a, b));
    return *reinterpret_cast<unsigned int*>(&h);
}
__device__ __forceinline__ float bf_lo(unsigned int u) {
    return __builtin_bit_cast(float, u << 16);
}
__device__ __forceinline__ float bf_hi(unsigned int u) {
    return __builtin_bit_cast(float, u & 0xffff0000u);
}

// ---------------- P1: wcast — W2 (64 blocks) + W1 (192 blocks) -> frag bf16 ----------------
__global__ __launch_bounds__(256) void wcast_kernel(
    const float* __restrict__ W1, const float* __restrict__ W2,
    unsigned short* __restrict__ W1F, unsigned short* __restrict__ W2F)
{
    __shared__ float tr[64 * 68];   // 17 KB
    const int t = threadIdx.x;
    const int id = blockIdx.x;

    const float* src;
    unsigned short* dst;
    int kt, nt;
    if (id < 64) { src = W2; dst = W2F; kt = id >> 3; nt = id & 7; }
    else         { src = W1; dst = W1F; kt = (id - 64) >> 3; nt = (id - 64) & 7; }
    const int k0 = kt * 64, n0 = nt * 64;

    {
        int r = t >> 2, c16 = (t & 3) * 16;
        #pragma unroll
        for (int q = 0; q < 4; ++q)
            *(float4*)&tr[r * 68 + c16 + q * 4] =
                *(const float4*)&src[(k0 + r) * 512 + n0 + c16 + q * 4];
    }
    __syncthreads();
    const int nl = t >> 2, kc16 = (t & 3) * 16;
    unsigned int pk[8];
    #pragma unroll
    for (int i = 0; i < 8; ++i) {
        float f0 = tr[(kc16 + 2 * i    ) * 68 + nl];
        float f1 = tr[(kc16 + 2 * i + 1) * 68 + nl];
        pk[i] = pack_bf16x2(f0, f1);
    }
    const int n  = n0 + nl;
    const int nf = n >> 4;
    #pragma unroll
    for (int h = 0; h < 2; ++h) {
        int kbase = k0 + kc16 + h * 8;
        int kc = kbase >> 5;
        int k8 = (kbase >> 3) & 3;
        int lane = (n & 15) + 16 * k8;
        uint4 v = h ? make_uint4(pk[4], pk[5], pk[6], pk[7])
                    : make_uint4(pk[0], pk[1], pk[2], pk[3]);
        *(uint4*)&dst[(unsigned)((kc * 32 + nf) * 512 + lane * 8)] = v;
    }
}

// ---------------- P2: l1 — MFMA GEMM for layer 1 ----------------
// grid 18 x 512: blocks 0..1 -> hz (g_q @ W1[:1024] + b1 -> f32 hzb, K=1024)
//                blocks 2..17 -> hp (Phi @ W1[1024:] -> bf16 hpb, K=512)
// Block 64 rows x 512 cols, 8 waves, wave 64x64 (acc 4x4). A staged f32->bf16
// in LDS (swizzled); B frags global->reg from W1F (prefetched at body top).
__global__ __launch_bounds__(512) void l1_kernel(
    const float* __restrict__ g_q, const float* __restrict__ Phi,
    const unsigned short* __restrict__ W1F, const float* __restrict__ b1,
    float* __restrict__ hzb, unsigned short* __restrict__ hpb)
{
    __shared__ __align__(16) unsigned short lA[64 * 64];   // 8 KB

    const int t = threadIdx.x;
    const int w = t >> 6;
    const int l = t & 63;
    const int bi = blockIdx.x;
    const bool is_hz = bi < 2;
    const int r0 = is_hz ? bi * 64 : (bi - 2) * 64;
    const int ld = is_hz ? 1024 : 512;
    const int nkt = is_hz ? 16 : 8;
    const int kcb = is_hz ? 0 : 32;
    const float* src = is_hz ? g_q : Phi;

    f32x4 acc[4][4];
    #pragma unroll
    for (int a = 0; a < 4; ++a)
        #pragma unroll
        for (int bf = 0; bf < 4; ++bf)
            acc[a][bf] = f32x4{0.f, 0.f, 0.f, 0.f};

    const int arow = t >> 3;
    const int ac   = t & 7;
    const float* srow = src + (unsigned)(r0 + arow) * ld;
    const unsigned int awoff = (unsigned)(arow * 128 + ((ac ^ (arow & 7)) << 4));

    #pragma unroll 1
    for (int kt = 0; kt < nkt; ++kt) {
        // B(kt) frags (issued first; consumed after stage+barrier)
        uint4 breg[2][4];
        #pragma unroll
        for (int kk = 0; kk < 2; ++kk)
            #pragma unroll
            for (int bf = 0; bf < 4; ++bf)
                breg[kk][bf] = *(const uint4*)
                    &W1F[(unsigned)(((kcb + kt * 2 + kk) * 32 + w * 4 + bf) * 512 + l * 8)];

        // stage A(kt): f32 -> bf16, swizzled
        {
            float4 p0 = *(const float4*)&srow[kt * 64 + ac * 8];
            float4 p1 = *(const float4*)&srow[kt * 64 + ac * 8 + 4];
            uint4 pk;
            pk.x = pack_bf16x2(p0.x, p0.y);
            pk.y = pack_bf16x2(p0.z, p0.w);
            pk.z = pack_bf16x2(p1.x, p1.y);
            pk.w = pack_bf16x2(p1.z, p1.w);
            *(uint4*)((char*)lA + awoff) = pk;
        }
        __syncthreads();

        #pragma unroll
        for (int kk = 0; kk < 2; ++kk) {
            const int cch = kk * 4 + (l >> 4);
            bf16x8 af[4];
            #pragma unroll
            for (int a = 0; a < 4; ++a) {
                int row = 16 * a + (l & 15);
                unsigned off = (unsigned)(row * 128 + ((cch ^ (row & 7)) << 4));
                af[a] = __builtin_bit_cast(bf16x8, *(const uint4*)((const char*)lA + off));
            }
            #pragma unroll
            for (int bf = 0; bf < 4; ++bf) {
                bf16x8 bfr = __builtin_bit_cast(bf16x8, breg[kk][bf]);
                #pragma unroll
                for (int a = 0; a < 4; ++a)
                    acc[a][bf] = __builtin_amdgcn_mfma_f32_16x16x32_bf16(
                        af[a], bfr, acc[a][bf], 0, 0, 0);
            }
        }
        __syncthreads();
    }

    // epilogue: store (C layout: col=l&15, row=(l>>4)*4+r within 16x16 tile)
    const int cl = l & 15, rq = (l >> 4) * 4;
    #pragma unroll
    for (int bf = 0; bf < 4; ++bf) {
        int n = w * 64 + 16 * bf + cl;
        if (is_hz) {
            float bb = b1[n];
            #pragma unroll
            for (int a = 0; a < 4; ++a)
                #pragma unroll
                for (int r = 0; r < 4; ++r)
                    hzb[(unsigned)(r0 + 16 * a + rq + r) * 512 + n] = acc[a][bf][r] + bb;
        } else {
            #pragma unroll
            for (int a = 0; a < 4; ++a)
                #pragma unroll
                for (int r = 0; r < 4; ++r) {
                    __hip_bfloat16 v = __float2bfloat16(acc[a][bf][r]);
                    hpb[(unsigned)(r0 + 16 * a + rq + r) * 512 + n] =
                        *reinterpret_cast<unsigned short*>(&v);
                }
        }
    }
}

// ---------------- fused: gelu1 -> bf16 GEMM (x W2) -> gelu2 -> dot W3 ----------------
// Block: 64 rows x 512 cols, 512 thr (8 waves), wave 64x64 (acc 4x4).
// A (gelu1) LDS double-buffered 2x8KB swizzled; B frags global->reg (W2F).
// Pipeline: hv prefetched 2 kt ahead; B(kt+1) issued right after MFMA(kt)
// consumes breg (~400cyc to use). ONE barrier per kt. setprio around MFMA.
__global__ __launch_bounds__(512, 2) void fused_kernel(
    const float* __restrict__ hzb, const unsigned short* __restrict__ hpb,
    const unsigned short* __restrict__ W2F,
    const float* __restrict__ b2, const float* __restrict__ W3,
    const float* __restrict__ b3, float* __restrict__ out)
{
    __shared__ __align__(16) unsigned short lA[2 * 64 * 64]; // 16 KB
    __shared__ __align__(16) float lhz[512];
    __shared__ float lred[8][64];

    const int t = threadIdx.x;
    const int w = t >> 6;
    const int l = t & 63;
    const int r0 = blockIdx.x * 64;
    const int b  = r0 >> 10;
    const int m0 = r0 & 1023;

    f32x4 acc[4][4];
    #pragma unroll
    for (int a = 0; a < 4; ++a)
        #pragma unroll
        for (int bf = 0; bf < 4; ++bf)
            acc[a][bf] = f32x4{0.f, 0.f, 0.f, 0.f};

    const int arow = t >> 3;
    const int ac   = t & 7;
    const unsigned short* hprow = hpb + (unsigned)(m0 + arow) * 512;
    const float4* lhz4 = (const float4*)lhz;
    const unsigned int awoff = (unsigned)(arow * 128 + ((ac ^ (arow & 7)) << 4));

    auto AGEN = [&](uint4 hv, int kt, int buf) {
        const int kb = kt * 64 + ac * 8;
        float4 z0 = lhz4[kb >> 2];
        float4 z1 = lhz4[(kb >> 2) + 1];
        float g0 = gelu_f(bf_lo(hv.x) + z0.x);
        float g1 = gelu_f(bf_hi(hv.x) + z0.y);
        float g2 = gelu_f(bf_lo(hv.y) + z0.z);
        float g3 = gelu_f(bf_hi(hv.y) + z0.w);
        float g4 = gelu_f(bf_lo(hv.z) + z1.x);
        float g5 = gelu_f(bf_hi(hv.z) + z1.y);
        float g6 = gelu_f(bf_lo(hv.w) + z1.z);
        float g7 = gelu_f(bf_hi(hv.w) + z1.w);
        uint4 pk;
        pk.x = pack_bf16x2(g0, g1);
        pk.y = pack_bf16x2(g2, g3);
        pk.z = pack_bf16x2(g4, g5);
        pk.w = pack_bf16x2(g6, g7);
        *(uint4*)((char*)lA + (unsigned)(buf * 8192) + awoff) = pk;
    };

    auto BLOAD = [&](int kt, uint4 breg[2][4]) {
        #pragma unroll
        for (int kk = 0; kk < 2; ++kk)
            #pragma unroll
            for (int bf = 0; bf < 4; ++bf)
                breg[kk][bf] = *(const uint4*)
                    &W2F[(unsigned)(((kt * 2 + kk) * 32 + w * 4 + bf) * 512 + l * 8)];
    };

    // ---- prologue ----
    uint4 hvC = *(const uint4*)&hprow[ac * 8];      // hp(0)
    uint4 breg[2][4];
    BLOAD(0, breg);
    lhz[t] = hzb[b * 512 + t];
    __syncthreads();            // lhz visible
    AGEN(hvC, 0, 0);
    hvC = *(const uint4*)&hprow[64 + ac * 8];       // hp(1)
    __syncthreads();            // lA[0] ready

    // ---- main loop: one barrier per kt ----
    #pragma unroll 2
    for (int kt = 0; kt < 8; ++kt) {
        uint4 hvN;
        if (kt < 6) hvN = *(const uint4*)&hprow[(kt + 2) * 64 + ac * 8];

        if (kt < 7) AGEN(hvC, kt + 1, (kt + 1) & 1);

        // MFMA(kt)
        const char* abase = (const char*)lA + (kt & 1) * 8192;
        __builtin_amdgcn_s_setprio(1);
        #pragma unroll
        for (int kk = 0; kk < 2; ++kk) {
            const int cch = kk * 4 + (l >> 4);
            bf16x8 af[4];
            #pragma unroll
            for (int a = 0; a < 4; ++a) {
                int row = 16 * a + (l & 15);
                unsigned off = (unsigned)(row * 128 + ((cch ^ (row & 7)) << 4));
                af[a] = __builtin_bit_cast(bf16x8, *(const uint4*)(abase + off));
            }
            #pragma unroll
            for (int bf = 0; bf < 4; ++bf) {
                bf16x8 bfr = __builtin_bit_cast(bf16x8, breg[kk][bf]);
                #pragma unroll
                for (int a = 0; a < 4; ++a)
                    acc[a][bf] = __builtin_amdgcn_mfma_f32_16x16x32_bf16(
                        af[a], bfr, acc[a][bf], 0, 0, 0);
            }
        }
        __builtin_amdgcn_s_setprio(0);

        if (kt < 7) BLOAD(kt + 1, breg);    // after consumption; ~400cyc to use
        if (kt < 6) hvC = hvN;

        __syncthreads();        // lA[(kt+1)&1] published; lA[kt&1] free
    }

    // ---- epilogue: +b2, gelu2, dot W3, reduce ----
    float b2v[4], w3v[4];
    #pragma unroll
    for (int bf = 0; bf < 4; ++bf) {
        int n = w * 64 + 16 * bf + (l & 15);
        b2v[bf] = b2[n];
        w3v[bf] = W3[n];
    }
    float psum[4][4];
    #pragma unroll
    for (int a = 0; a < 4; ++a)
        #pragma unroll
        for (int r = 0; r < 4; ++r) psum[a][r] = 0.f;

    #pragma unroll
    for (int bf = 0; bf < 4; ++bf)
        #pragma unroll
        for (int a = 0; a < 4; ++a)
            #pragma unroll
            for (int r = 0; r < 4; ++r) {
                float x = acc[a][bf][r] + b2v[bf];
                float h = gelu_f(x);
                psum[a][r] = __builtin_fmaf(h, w3v[bf], psum[a][r]);
            }

    #pragma unroll
    for (int a = 0; a < 4; ++a)
        #pragma unroll
        for (int r = 0; r < 4; ++r) {
            float v = psum[a][r];
            v += __shfl_xor(v, 1);
            v += __shfl_xor(v, 2);
            v += __shfl_xor(v, 4);
            v += __shfl_xor(v, 8);
            psum[a][r] = v;
        }

    if ((l & 15) == 0) {
        int gb = (l >> 4) * 4;
        #pragma unroll
        for (int a = 0; a < 4; ++a)
            #pragma unroll
            for (int r = 0; r < 4; ++r)
                lred[w][16 * a + gb + r] = psum[a][r];
    }
    __syncthreads();
    if (t < 64) {
        float s = b3[0];
        #pragma unroll
        for (int ww = 0; ww < 8; ++ww) s += lred[ww][t];
        out[r0 + t] = s;
    }
}

extern "C" void kernel_launch(void* const* d_in, const int* in_sizes, int n_in,
                              void* d_out, int out_size, void* d_ws, size_t ws_size,
                              hipStream_t stream) {
    (void)in_sizes; (void)n_in; (void)out_size; (void)ws_size;
    const float* g_q = (const float*)d_in[0];
    const float* Phi = (const float*)d_in[1];
    const float* W1  = (const float*)d_in[2];
    const float* b1  = (const float*)d_in[3];
    const float* W2  = (const float*)d_in[4];
    const float* b2  = (const float*)d_in[5];
    const float* W3  = (const float*)d_in[6];
    const float* b3  = (const float*)d_in[7];
    float* out = (float*)d_out;

    char* ws = (char*)d_ws;
    float*          hzb = (float*)ws;                                    // 256 KB
    unsigned short* hpb = (unsigned short*)(ws + 262144);                // 1 MB
    unsigned short* W2F = (unsigned short*)(ws + 1310720);               // 512 KB
    unsigned short* W1F = (unsigned short*)(ws + 1835008);               // 1.5 MB

    hipLaunchKernelGGL(wcast_kernel, dim3(256), dim3(256), 0, stream,
                       W1, W2, W1F, W2F);
    hipLaunchKernelGGL(l1_kernel, dim3(18), dim3(512), 0, stream,
                       g_q, Phi, W1F, b1, hzb, hpb);
    hipLaunchKernelGGL(fused_kernel, dim3(2048), dim3(512), 0, stream,
                       hzb, hpb, W2F, b2, W3, b3, out);
}

// Round 6
// 132.565 us; speedup vs baseline: 1.4468x; 1.0333x over previous
//
#include <hip/hip_runtime.h>
#include <hip/hip_bf16.h>

// Sizes (fixed): B=128, M=1024, D_Z=1024, D_PHI=512, H1=512, H2=512
// ws: hzb f32[128*512] @0 (256KB) | hpb bf16[1024*512] @256K (1MB) |
//     W2F bf16[512*512] @1.25M (512KB) | W1F bf16[1536*512] @1.75M (1.5MB)
//
// Frag layout (W1F, W2F): B-fragment for (kc = k>>5, nf = n>>4) is 1024B
// contiguous: addr_ushort = (kc*32 + nf)*512 + lane*8,
//   lane = (n&15) + 16*((k>>3)&3), holds W[k..k+7][n]  (exact 16x16x32 B-frag).

typedef __bf16 bf16x8 __attribute__((ext_vector_type(8)));
typedef float  f32x4  __attribute__((ext_vector_type(4)));

// tanh-form GELU (max dev from exact erf ~5e-4)
__device__ __forceinline__ float gelu_f(float x) {
    float t = x * x;
    float inner = __builtin_fmaf(0.044715f * t, x, x);
    float e = __builtin_amdgcn_exp2f(2.3022082f * inner);
    float r = __builtin_amdgcn_rcpf(e + 1.0f);
    return __builtin_fmaf(-x, r, x);
}

__device__ __forceinline__ unsigned int pack_bf16x2(float a, float b) {
    __hip_bfloat162 h = __float22bfloat162_rn(make_float2(a, b));
    return *reinterpret_cast<unsigned int*>(&h);
}
__device__ __forceinline__ float bf_lo(unsigned int u) {
    return __builtin_bit_cast(float, u << 16);
}
__device__ __forceinline__ float bf_hi(unsigned int u) {
    return __builtin_bit_cast(float, u & 0xffff0000u);
}

// ---------------- P1: wcast — W2 (64 blocks) + W1 (192 blocks) -> frag bf16 ----------------
__global__ __launch_bounds__(256) void wcast_kernel(
    const float* __restrict__ W1, const float* __restrict__ W2,
    unsigned short* __restrict__ W1F, unsigned short* __restrict__ W2F)
{
    __shared__ float tr[64 * 68];   // 17 KB
    const int t = threadIdx.x;
    const int id = blockIdx.x;

    const float* src;
    unsigned short* dst;
    int kt, nt;
    if (id < 64) { src = W2; dst = W2F; kt = id >> 3; nt = id & 7; }
    else         { src = W1; dst = W1F; kt = (id - 64) >> 3; nt = (id - 64) & 7; }
    const int k0 = kt * 64, n0 = nt * 64;

    {
        int r = t >> 2, c16 = (t & 3) * 16;
        #pragma unroll
        for (int q = 0; q < 4; ++q)
            *(float4*)&tr[r * 68 + c16 + q * 4] =
                *(const float4*)&src[(k0 + r) * 512 + n0 + c16 + q * 4];
    }
    __syncthreads();
    const int nl = t >> 2, kc16 = (t & 3) * 16;
    unsigned int pk[8];
    #pragma unroll
    for (int i = 0; i < 8; ++i) {
        float f0 = tr[(kc16 + 2 * i    ) * 68 + nl];
        float f1 = tr[(kc16 + 2 * i + 1) * 68 + nl];
        pk[i] = pack_bf16x2(f0, f1);
    }
    const int n  = n0 + nl;
    const int nf = n >> 4;
    #pragma unroll
    for (int h = 0; h < 2; ++h) {
        int kbase = k0 + kc16 + h * 8;
        int kc = kbase >> 5;
        int k8 = (kbase >> 3) & 3;
        int lane = (n & 15) + 16 * k8;
        uint4 v = h ? make_uint4(pk[4], pk[5], pk[6], pk[7])
                    : make_uint4(pk[0], pk[1], pk[2], pk[3]);
        *(uint4*)&dst[(unsigned)((kc * 32 + nf) * 512 + lane * 8)] = v;
    }
}

// ---------------- P2: l1 — MFMA GEMM for layer 1 ----------------
// grid 18 x 512: blocks 0..1 -> hz (g_q @ W1[:1024] + b1 -> f32 hzb, K=1024)
//                blocks 2..17 -> hp (Phi @ W1[1024:] -> bf16 hpb, K=512)
__global__ __launch_bounds__(512) void l1_kernel(
    const float* __restrict__ g_q, const float* __restrict__ Phi,
    const unsigned short* __restrict__ W1F, const float* __restrict__ b1,
    float* __restrict__ hzb, unsigned short* __restrict__ hpb)
{
    __shared__ __align__(16) unsigned short lA[64 * 64];   // 8 KB

    const int t = threadIdx.x;
    const int w = t >> 6;
    const int l = t & 63;
    const int bi = blockIdx.x;
    const bool is_hz = bi < 2;
    const int r0 = is_hz ? bi * 64 : (bi - 2) * 64;
    const int ld = is_hz ? 1024 : 512;
    const int nkt = is_hz ? 16 : 8;
    const int kcb = is_hz ? 0 : 32;
    const float* src = is_hz ? g_q : Phi;

    f32x4 acc[4][4];
    #pragma unroll
    for (int a = 0; a < 4; ++a)
        #pragma unroll
        for (int bf = 0; bf < 4; ++bf)
            acc[a][bf] = f32x4{0.f, 0.f, 0.f, 0.f};

    const int arow = t >> 3;
    const int ac   = t & 7;
    const float* srow = src + (unsigned)(r0 + arow) * ld;
    const unsigned int awoff = (unsigned)(arow * 128 + ((ac ^ (arow & 7)) << 4));

    #pragma unroll 1
    for (int kt = 0; kt < nkt; ++kt) {
        uint4 breg[2][4];
        #pragma unroll
        for (int kk = 0; kk < 2; ++kk)
            #pragma unroll
            for (int bf = 0; bf < 4; ++bf)
                breg[kk][bf] = *(const uint4*)
                    &W1F[(unsigned)(((kcb + kt * 2 + kk) * 32 + w * 4 + bf) * 512 + l * 8)];

        {
            float4 p0 = *(const float4*)&srow[kt * 64 + ac * 8];
            float4 p1 = *(const float4*)&srow[kt * 64 + ac * 8 + 4];
            uint4 pk;
            pk.x = pack_bf16x2(p0.x, p0.y);
            pk.y = pack_bf16x2(p0.z, p0.w);
            pk.z = pack_bf16x2(p1.x, p1.y);
            pk.w = pack_bf16x2(p1.z, p1.w);
            *(uint4*)((char*)lA + awoff) = pk;
        }
        __syncthreads();

        #pragma unroll
        for (int kk = 0; kk < 2; ++kk) {
            const int cch = kk * 4 + (l >> 4);
            bf16x8 af[4];
            #pragma unroll
            for (int a = 0; a < 4; ++a) {
                int row = 16 * a + (l & 15);
                unsigned off = (unsigned)(row * 128 + ((cch ^ (row & 7)) << 4));
                af[a] = __builtin_bit_cast(bf16x8, *(const uint4*)((const char*)lA + off));
            }
            #pragma unroll
            for (int bf = 0; bf < 4; ++bf) {
                bf16x8 bfr = __builtin_bit_cast(bf16x8, breg[kk][bf]);
                #pragma unroll
                for (int a = 0; a < 4; ++a)
                    acc[a][bf] = __builtin_amdgcn_mfma_f32_16x16x32_bf16(
                        af[a], bfr, acc[a][bf], 0, 0, 0);
            }
        }
        __syncthreads();
    }

    const int cl = l & 15, rq = (l >> 4) * 4;
    #pragma unroll
    for (int bf = 0; bf < 4; ++bf) {
        int n = w * 64 + 16 * bf + cl;
        if (is_hz) {
            float bb = b1[n];
            #pragma unroll
            for (int a = 0; a < 4; ++a)
                #pragma unroll
                for (int r = 0; r < 4; ++r)
                    hzb[(unsigned)(r0 + 16 * a + rq + r) * 512 + n] = acc[a][bf][r] + bb;
        } else {
            #pragma unroll
            for (int a = 0; a < 4; ++a)
                #pragma unroll
                for (int r = 0; r < 4; ++r) {
                    __hip_bfloat16 v = __float2bfloat16(acc[a][bf][r]);
                    hpb[(unsigned)(r0 + 16 * a + rq + r) * 512 + n] =
                        *reinterpret_cast<unsigned short*>(&v);
                }
        }
    }
}

// ---------------- fused: gelu1 -> bf16 GEMM (x W2) -> gelu2 -> dot W3 ----------------
// Round-4 structure + depth-1 cross-barrier register prefetch:
//   body kt: load hv[kt&1]=hp(kt+2); AGEN(kt+1); MFMA(kt,kk0)<bA>; bA<-B(kt+1,kk0);
//            MFMA(kt,kk1)<bB>; bB<-B(kt+1,kk1); barrier.
// Every global load has >=1 full body (~700+ cyc) of cover. No setprio.
__global__ __launch_bounds__(512, 2) void fused_kernel(
    const float* __restrict__ hzb, const unsigned short* __restrict__ hpb,
    const unsigned short* __restrict__ W2F,
    const float* __restrict__ b2, const float* __restrict__ W3,
    const float* __restrict__ b3, float* __restrict__ out)
{
    __shared__ __align__(16) unsigned short lA[2 * 64 * 64]; // 16 KB
    __shared__ __align__(16) float lhz[512];
    __shared__ float lred[8][64];

    const int t = threadIdx.x;
    const int w = t >> 6;
    const int l = t & 63;
    const int r0 = blockIdx.x * 64;
    const int b  = r0 >> 10;
    const int m0 = r0 & 1023;

    f32x4 acc[4][4];
    #pragma unroll
    for (int a = 0; a < 4; ++a)
        #pragma unroll
        for (int bf = 0; bf < 4; ++bf)
            acc[a][bf] = f32x4{0.f, 0.f, 0.f, 0.f};

    const int arow = t >> 3;
    const int ac   = t & 7;
    const unsigned short* hprow = hpb + (unsigned)(m0 + arow) * 512;
    const float4* lhz4 = (const float4*)lhz;
    const unsigned int awoff = (unsigned)(arow * 128 + ((ac ^ (arow & 7)) << 4));

    auto AGEN = [&](uint4 hv, int kt, int buf) {
        const int kb = kt * 64 + ac * 8;
        float4 z0 = lhz4[kb >> 2];
        float4 z1 = lhz4[(kb >> 2) + 1];
        float g0 = gelu_f(bf_lo(hv.x) + z0.x);
        float g1 = gelu_f(bf_hi(hv.x) + z0.y);
        float g2 = gelu_f(bf_lo(hv.y) + z0.z);
        float g3 = gelu_f(bf_hi(hv.y) + z0.w);
        float g4 = gelu_f(bf_lo(hv.z) + z1.x);
        float g5 = gelu_f(bf_hi(hv.z) + z1.y);
        float g6 = gelu_f(bf_lo(hv.w) + z1.z);
        float g7 = gelu_f(bf_hi(hv.w) + z1.w);
        uint4 pk;
        pk.x = pack_bf16x2(g0, g1);
        pk.y = pack_bf16x2(g2, g3);
        pk.z = pack_bf16x2(g4, g5);
        pk.w = pack_bf16x2(g6, g7);
        *(uint4*)((char*)lA + (unsigned)(buf * 8192) + awoff) = pk;
    };

    auto BLOADK = [&](int kt, int kk, uint4 bfrag[4]) {
        #pragma unroll
        for (int bf = 0; bf < 4; ++bf)
            bfrag[bf] = *(const uint4*)
                &W2F[(unsigned)(((kt * 2 + kk) * 32 + w * 4 + bf) * 512 + l * 8)];
    };

    auto MFMA_HALF = [&](const char* abase, int kk, uint4 bfrag[4]) {
        const int cch = kk * 4 + (l >> 4);
        bf16x8 af[4];
        #pragma unroll
        for (int a = 0; a < 4; ++a) {
            int row = 16 * a + (l & 15);
            unsigned off = (unsigned)(row * 128 + ((cch ^ (row & 7)) << 4));
            af[a] = __builtin_bit_cast(bf16x8, *(const uint4*)(abase + off));
        }
        #pragma unroll
        for (int bf = 0; bf < 4; ++bf) {
            bf16x8 bfr = __builtin_bit_cast(bf16x8, bfrag[bf]);
            #pragma unroll
            for (int a = 0; a < 4; ++a)
                acc[a][bf] = __builtin_amdgcn_mfma_f32_16x16x32_bf16(
                    af[a], bfr, acc[a][bf], 0, 0, 0);
        }
    };

    // ---- prologue ----
    uint4 bA[4], bB[4], hv[2];
    uint4 hv_pro = *(const uint4*)&hprow[ac * 8];   // hp(0)
    BLOADK(0, 0, bA);
    BLOADK(0, 1, bB);
    lhz[t] = hzb[b * 512 + t];
    __syncthreads();                 // lhz visible
    AGEN(hv_pro, 0, 0);
    hv[1] = *(const uint4*)&hprow[64 + ac * 8];     // hp(1), used body0's AGEN(1)
    __syncthreads();                 // lA[0] ready

    // ---- main loop ----
    #pragma unroll 2
    for (int kt = 0; kt < 8; ++kt) {
        if (kt < 6)
            hv[kt & 1] = *(const uint4*)&hprow[(kt + 2) * 64 + ac * 8];  // hp(kt+2)

        if (kt < 7) AGEN(hv[(kt + 1) & 1], kt + 1, (kt + 1) & 1);

        const char* abase = (const char*)lA + (kt & 1) * 8192;
        MFMA_HALF(abase, 0, bA);
        if (kt < 7) BLOADK(kt + 1, 0, bA);      // crosses barrier in flight
        MFMA_HALF(abase, 1, bB);
        if (kt < 7) BLOADK(kt + 1, 1, bB);      // crosses barrier in flight

        __syncthreads();            // lA[(kt+1)&1] published; lA[kt&1] free
    }

    // ---- epilogue: +b2, gelu2, dot W3, reduce ----
    float b2v[4], w3v[4];
    #pragma unroll
    for (int bf = 0; bf < 4; ++bf) {
        int n = w * 64 + 16 * bf + (l & 15);
        b2v[bf] = b2[n];
        w3v[bf] = W3[n];
    }
    float psum[4][4];
    #pragma unroll
    for (int a = 0; a < 4; ++a)
        #pragma unroll
        for (int r = 0; r < 4; ++r) psum[a][r] = 0.f;

    #pragma unroll
    for (int bf = 0; bf < 4; ++bf)
        #pragma unroll
        for (int a = 0; a < 4; ++a)
            #pragma unroll
            for (int r = 0; r < 4; ++r) {
                float x = acc[a][bf][r] + b2v[bf];
                float h = gelu_f(x);
                psum[a][r] = __builtin_fmaf(h, w3v[bf], psum[a][r]);
            }

    #pragma unroll
    for (int a = 0; a < 4; ++a)
        #pragma unroll
        for (int r = 0; r < 4; ++r) {
            float v = psum[a][r];
            v += __shfl_xor(v, 1);
            v += __shfl_xor(v, 2);
            v += __shfl_xor(v, 4);
            v += __shfl_xor(v, 8);
            psum[a][r] = v;
        }

    if ((l & 15) == 0) {
        int gb = (l >> 4) * 4;
        #pragma unroll
        for (int a = 0; a < 4; ++a)
            #pragma unroll
            for (int r = 0; r < 4; ++r)
                lred[w][16 * a + gb + r] = psum[a][r];
    }
    __syncthreads();
    if (t < 64) {
        float s = b3[0];
        #pragma unroll
        for (int ww = 0; ww < 8; ++ww) s += lred[ww][t];
        out[r0 + t] = s;
    }
}

extern "C" void kernel_launch(void* const* d_in, const int* in_sizes, int n_in,
                              void* d_out, int out_size, void* d_ws, size_t ws_size,
                              hipStream_t stream) {
    (void)in_sizes; (void)n_in; (void)out_size; (void)ws_size;
    const float* g_q = (const float*)d_in[0];
    const float* Phi = (const float*)d_in[1];
    const float* W1  = (const float*)d_in[2];
    const float* b1  = (const float*)d_in[3];
    const float* W2  = (const float*)d_in[4];
    const float* b2  = (const float*)d_in[5];
    const float* W3  = (const float*)d_in[6];
    const float* b3  = (const float*)d_in[7];
    float* out = (float*)d_out;

    char* ws = (char*)d_ws;
    float*          hzb = (float*)ws;                                    // 256 KB
    unsigned short* hpb = (unsigned short*)(ws + 262144);                // 1 MB
    unsigned short* W2F = (unsigned short*)(ws + 1310720);               // 512 KB
    unsigned short* W1F = (unsigned short*)(ws + 1835008);               // 1.5 MB

    hipLaunchKernelGGL(wcast_kernel, dim3(256), dim3(256), 0, stream,
                       W1, W2, W1F, W2F);
    hipLaunchKernelGGL(l1_kernel, dim3(18), dim3(512), 0, stream,
                       g_q, Phi, W1F, b1, hzb, hpb);
    hipLaunchKernelGGL(fused_kernel, dim3(2048), dim3(512), 0, stream,
                       hzb, hpb, W2F, b2, W3, b3, out);
}